// Round 8
// baseline (205.402 us; speedup 1.0000x reference)
//
#include <hip/hip_runtime.h>
#include <hip/hip_bf16.h>

#define CCH 256
#define NSEQ 2048
#define BATCH 8

typedef __hip_bfloat16 bf16;
typedef short s8v __attribute__((ext_vector_type(8)));    // 8 bf16 (A/B frag)
typedef float f4v __attribute__((ext_vector_type(4)));    // 16x16 C/D frag
typedef float f16v __attribute__((ext_vector_type(16)));  // 32x32 C/D frag

struct __align__(8) bf16x4 { bf16 v[4]; };

__device__ __forceinline__ float b2f(bf16 h) { return __bfloat162float(h); }
__device__ __forceinline__ bf16 f2b(float f) { return __float2bfloat16(f); }

#define MFMA16(a, b, c) __builtin_amdgcn_mfma_f32_16x16x32_bf16((a), (b), (c), 0, 0, 0)
#define MFMA32(a, b, c) __builtin_amdgcn_mfma_f32_32x32x16_bf16((a), (b), (c), 0, 0, 0)

// async global->LDS 16B per lane: lds dest = uniform base + lane*16
__device__ __forceinline__ void gload_lds16(const bf16* g, bf16* l) {
    __builtin_amdgcn_global_load_lds(
        (const __attribute__((address_space(1))) unsigned int*)(g),
        (__attribute__((address_space(3))) unsigned int*)(l), 16, 0, 0);
}

// ---------------------------------------------------------------------------
// prepw: cast the four 256x256 weight matrices fp32 -> bf16.
// ---------------------------------------------------------------------------
__global__ __launch_bounds__(256) void prepw_kernel(
    const float* __restrict__ wq, const float* __restrict__ wk,
    const float* __restrict__ wv, const float* __restrict__ wo,
    bf16* __restrict__ wqb, bf16* __restrict__ wkb,
    bf16* __restrict__ wvb, bf16* __restrict__ wob)
{
    int base = (blockIdx.x * 256 + threadIdx.x) * 8;   // 128*256*8 = 4*65536
    int mat = base >> 16, off = base & 65535;
    const float* s = (mat == 0) ? wq : (mat == 1) ? wk : (mat == 2) ? wv : wo;
    bf16* d       = (mat == 0) ? wqb : (mat == 1) ? wkb : (mat == 2) ? wvb : wob;
    #pragma unroll
    for (int j = 0; j < 8; ++j) d[off + j] = f2b(s[off + j]);
}

// ---------------------------------------------------------------------------
// qkv v8: NO scattered global stores. Grid (256 tiles, 2 phases), 2 blocks/CU.
// Stage x tile transposed in LDS -> xf regs. Each projection: MFMA -> D-tile
// scalar writes into (dead) xs buffer (<=2-way banks) -> row-wise b128 reads
// -> 1KB-coalesced global stores.
//   q/k: T64 tile-major [tile][cblk=c/8][n64][8]  (flash-coalesced)
//   v:   frag-major Vf [b][mc=m/16][cb=c/32][c32][h][8]  (flash-coalesced)
//   phase 0: q (256c) + k (c 0..127); phase 1: v (256c) + k (c 128..255)
// ---------------------------------------------------------------------------
__global__ __launch_bounds__(256, 2) void qkv_kernel(
    const float* __restrict__ x,
    const bf16* __restrict__ Wq, const bf16* __restrict__ Wk,
    const bf16* __restrict__ Wv,
    const float* __restrict__ bq, const float* __restrict__ bk,
    const float* __restrict__ bv,
    bf16* __restrict__ qTt, bf16* __restrict__ kTt, bf16* __restrict__ Vf)
{
    __shared__ bf16 xs[64][260];   // staging + repack buffer (33,280 B)
    bf16(*rsv)[18] = (bf16(*)[18])&xs[0][0];   // v-repack view [256c][18]

    const int tile = blockIdx.x;
    const int flat0 = tile * 64;
    const int phase = blockIdx.y;
    const int b = flat0 >> 11, nn = flat0 & 2047;
    const int tid = threadIdx.x;
    const int w = tid >> 6, lane = tid & 63;
    const int l15 = lane & 15, quad = lane >> 4;
    const float* xb = x + (size_t)b * CCH * NSEQ;

    // stage + transpose x tile (fp32 [c][n] -> bf16 xs[n][c])
    #pragma unroll
    for (int i = 0; i < 16; ++i) {
        int f4i = i * 256 + tid;
        int c = f4i >> 4, nq = f4i & 15;
        float4 v4 = *(const float4*)&xb[(size_t)c * NSEQ + nn + nq * 4];
        xs[nq * 4 + 0][c] = f2b(v4.x);
        xs[nq * 4 + 1][c] = f2b(v4.y);
        xs[nq * 4 + 2][c] = f2b(v4.z);
        xs[nq * 4 + 3][c] = f2b(v4.w);
    }
    __syncthreads();                     // B1: xs staged

    s8v xf[8];                           // wave w's rows (A- or B-frag)
    #pragma unroll
    for (int t = 0; t < 8; ++t)
        xf[t] = *(const s8v*)&xs[w * 16 + l15][t * 32 + quad * 8];
    __syncthreads();                     // B2: xs now dead -> repack buffer

    bf16* qt = qTt + (size_t)tile * 16384;
    bf16* kt = kTt + (size_t)tile * 16384;

    if (phase == 0) {
        // ---- q: D[n][c], all 256 c ----
        #pragma unroll 2
        for (int cs = 0; cs < 16; ++cs) {
            const s8v* wr = (const s8v*)(Wq + (size_t)(cs * 16 + l15) * CCH);
            f4v a = {};
            #pragma unroll
            for (int t = 0; t < 8; ++t) a = MFMA16(xf[t], wr[t * 4 + quad], a);
            int c = cs * 16 + l15;
            float bb = bq[c];
            #pragma unroll
            for (int r = 0; r < 4; ++r)
                xs[w * 16 + quad * 4 + r][c] = f2b((a[r] + bb) * 0.0625f);
        }
        __syncthreads();                 // B3: q tile in xs
        #pragma unroll
        for (int i = 0; i < 8; ++i) {
            int cblk = w * 8 + i;
            s8v row = *(const s8v*)&xs[lane][cblk * 8];
            *(s8v*)&qt[cblk * 512 + lane * 8] = row;
        }
        __syncthreads();                 // B4: q read out
        // ---- k half 1: c 0..127 ----
        #pragma unroll 2
        for (int cs = 0; cs < 8; ++cs) {
            const s8v* wr = (const s8v*)(Wk + (size_t)(cs * 16 + l15) * CCH);
            f4v a = {};
            #pragma unroll
            for (int t = 0; t < 8; ++t) a = MFMA16(xf[t], wr[t * 4 + quad], a);
            int c = cs * 16 + l15;
            float bb = bk[c];
            #pragma unroll
            for (int r = 0; r < 4; ++r)
                xs[w * 16 + quad * 4 + r][c] = f2b(a[r] + bb);
        }
        __syncthreads();                 // B5: k-half in xs
        #pragma unroll
        for (int i = 0; i < 4; ++i) {
            int cblk = w * 4 + i;        // 0..15
            s8v row = *(const s8v*)&xs[lane][cblk * 8];
            *(s8v*)&kt[cblk * 512 + lane * 8] = row;
        }
    } else {
        // ---- v: D[c][m], all 256 c; wave w owns m-chunk (nn>>4)+w ----
        #pragma unroll 2
        for (int cs = 0; cs < 16; ++cs) {
            const s8v* wr = (const s8v*)(Wv + (size_t)(cs * 16 + l15) * CCH);
            f4v a = {};
            #pragma unroll
            for (int t = 0; t < 8; ++t) a = MFMA16(wr[t * 4 + quad], xf[t], a);
            #pragma unroll
            for (int r = 0; r < 4; ++r) {
                int c = cs * 16 + quad * 4 + r;
                rsv[c][w * 0 + l15] = f2b(a[r] + bv[c]);   // per-wave region below
            }
        }
        // NOTE: rsv above must be per-wave; redo with offset (fix):
        __syncthreads();                 // B3 (placeholder ordering)
        __syncthreads();
    }
}

// The v-path above needs per-wave regions; implemented correctly in qkv2 below.
// (qkv_kernel phase 1 is unused; see qkv2_kernel.)

// ---------------------------------------------------------------------------
// qkv2: phase-1 replacement with correct per-wave v repack regions.
// rs layout: [4 wave][256 c][18 pad] bf16 = 36,864 B -> separate buffer.
// ---------------------------------------------------------------------------
__global__ __launch_bounds__(256, 2) void qkv2_kernel(
    const float* __restrict__ x,
    const bf16* __restrict__ Wk, const bf16* __restrict__ Wv,
    const float* __restrict__ bk, const float* __restrict__ bv,
    bf16* __restrict__ kTt, bf16* __restrict__ Vf)
{
    __shared__ bf16 xs[64][260];        // 33,280 B: staging + k repack
    __shared__ bf16 rv[4][256][18];     // 36,864 B: v repack (per wave)

    const int tile = blockIdx.x;
    const int flat0 = tile * 64;
    const int b = flat0 >> 11, nn = flat0 & 2047;
    const int tid = threadIdx.x;
    const int w = tid >> 6, lane = tid & 63;
    const int l15 = lane & 15, quad = lane >> 4;
    const int l31 = lane & 31, h = lane >> 5;
    const float* xb = x + (size_t)b * CCH * NSEQ;

    #pragma unroll
    for (int i = 0; i < 16; ++i) {
        int f4i = i * 256 + tid;
        int c = f4i >> 4, nq = f4i & 15;
        float4 v4 = *(const float4*)&xb[(size_t)c * NSEQ + nn + nq * 4];
        xs[nq * 4 + 0][c] = f2b(v4.x);
        xs[nq * 4 + 1][c] = f2b(v4.y);
        xs[nq * 4 + 2][c] = f2b(v4.z);
        xs[nq * 4 + 3][c] = f2b(v4.w);
    }
    __syncthreads();                     // B1

    s8v xf[8];
    #pragma unroll
    for (int t = 0; t < 8; ++t)
        xf[t] = *(const s8v*)&xs[w * 16 + l15][t * 32 + quad * 8];
    __syncthreads();                     // B2: xs dead

    // ---- v: D[c][m16] per wave -> rv[w] ----
    #pragma unroll 2
    for (int cs = 0; cs < 16; ++cs) {
        const s8v* wr = (const s8v*)(Wv + (size_t)(cs * 16 + l15) * CCH);
        f4v a = {};
        #pragma unroll
        for (int t = 0; t < 8; ++t) a = MFMA16(wr[t * 4 + quad], xf[t], a);
        #pragma unroll
        for (int r = 0; r < 4; ++r) {
            int c = cs * 16 + quad * 4 + r;
            rv[w][c][l15] = f2b(a[r] + bv[c]);
        }
    }
    // ---- k half 2: c 128..255 -> xs ----
    #pragma unroll 2
    for (int cs = 8; cs < 16; ++cs) {
        const s8v* wr = (const s8v*)(Wk + (size_t)(cs * 16 + l15) * CCH);
        f4v a = {};
        #pragma unroll
        for (int t = 0; t < 8; ++t) a = MFMA16(xf[t], wr[t * 4 + quad], a);
        int c = cs * 16 + l15;
        float bb = bk[c];
        #pragma unroll
        for (int r = 0; r < 4; ++r)
            xs[w * 16 + quad * 4 + r][c - 128] = f2b(a[r] + bb);
    }
    __syncthreads();                     // B3: rv + k-half ready

    // v readout: wave w -> m-chunk mc = (nn>>4)+w, coalesced 1KB stores
    bf16* Vfb = Vf + (size_t)b * CCH * NSEQ;
    const int mc = (nn >> 4) + w;
    #pragma unroll
    for (int cb = 0; cb < 8; ++cb) {
        s8v frag = *(const s8v*)&rv[w][cb * 32 + l31][h * 8];
        *(s8v*)&Vfb[(size_t)(mc * 8 + cb) * 512 + l31 * 16 + h * 8] = frag;
    }
    // k readout: cblk 16..31
    bf16* kt = kTt + (size_t)tile * 16384;
    #pragma unroll
    for (int i = 0; i < 4; ++i) {
        int cblk = w * 4 + i;            // local 0..15 -> global 16..31
        s8v row = *(const s8v*)&xs[lane][cblk * 8];
        *(s8v*)&kt[(16 + cblk) * 512 + lane * 8] = row;
    }
}

// ---------------------------------------------------------------------------
// flash v8 = R7 flash with frag-major Vf (coalesced 1KB V-frag loads).
// ---------------------------------------------------------------------------
__global__ __launch_bounds__(256, 2) void flash_kernel(
    const bf16* __restrict__ qTt, const bf16* __restrict__ kTt,
    const bf16* __restrict__ Vf, bf16* __restrict__ Opart,
    float* __restrict__ lpart)
{
    __shared__ bf16 Kc[16384];      // [cblk32][m64][8]  32,768 B
    __shared__ bf16 Ps[64][68];     // [n][m]  8,704 B
    __shared__ float l_s[2][64];

    const int b = blockIdx.x, nt = blockIdx.y, ms = blockIdx.z;
    const int tid = threadIdx.x;
    const int W = tid >> 6, lane = tid & 63;
    const int l31 = lane & 31, h = lane >> 5;
    const int ng = W >> 1, mg = W & 1;
    const int mb = ms * 16;
    const bf16* Vfb = Vf + (size_t)b * CCH * NSEQ;

    s8v qf[16];
    {
        const bf16* qt = qTt + (size_t)(b * 32 + nt) * 16384;
        #pragma unroll
        for (int t = 0; t < 16; ++t)
            qf[t] = *(const s8v*)&qt[(t * 2 + h) * 512 + (ng * 32 + l31) * 8];
    }

    f16v O[2][2] = {};
    float lacc[16] = {};

    {
        const bf16* kt = kTt + (size_t)(b * 32 + mb) * 16384;
        #pragma unroll
        for (int i = 0; i < 8; ++i) {
            int ch = W * 8 + i;
            gload_lds16(kt + ch * 512 + lane * 8, &Kc[ch * 512]);
        }
    }
    __syncthreads();

    for (int mt = 0; mt < 16; ++mt) {
        f16v S0 = {}, S1 = {};
        #pragma unroll
        for (int t = 0; t < 8; ++t) {
            s8v kf0 = *(const s8v*)&Kc[(t * 2 + h) * 512 + (mg * 32 + l31) * 8];
            s8v kf1 = *(const s8v*)&Kc[((t + 8) * 2 + h) * 512 + (mg * 32 + l31) * 8];
            S0 = MFMA32(qf[t], kf0, S0);
            S1 = MFMA32(qf[t + 8], kf1, S1);
        }
        // V A-frags: frag-major Vf -> fully coalesced (1KB per instr)
        s8v vf[2][4];
        #pragma unroll
        for (int ks = 0; ks < 4; ++ks) {
            int mc = (mb + mt) * 4 + ks;
            #pragma unroll
            for (int cr = 0; cr < 2; ++cr)
                vf[cr][ks] = *(const s8v*)&Vfb[
                    (size_t)(mc * 8 + W * 2 + cr) * 512 + l31 * 16 + h * 8];
        }
        #pragma unroll
        for (int reg = 0; reg < 16; ++reg) {
            float e = __expf(fminf(S0[reg] + S1[reg], 60.f));
            lacc[reg] += e;
            int row = (reg & 3) + 8 * (reg >> 2) + 4 * h;
            Ps[ng * 32 + row][mg * 32 + l31] = f2b(e);
        }
        __syncthreads();   // (B) Ps ready; QK reads of Kc done

        if (mt < 15) {
            const bf16* kt = kTt + (size_t)(b * 32 + mb + mt + 1) * 16384;
            #pragma unroll
            for (int i = 0; i < 8; ++i) {
                int ch = W * 8 + i;
                gload_lds16(kt + ch * 512 + lane * 8, &Kc[ch * 512]);
            }
        }
        #pragma unroll
        for (int ks = 0; ks < 4; ++ks) {
            s8v pf0 = *(const s8v*)&Ps[l31][ks * 16 + h * 8];
            s8v pf1 = *(const s8v*)&Ps[32 + l31][ks * 16 + h * 8];
            O[0][0] = MFMA32(vf[0][ks], pf0, O[0][0]);
            O[0][1] = MFMA32(vf[0][ks], pf1, O[0][1]);
            O[1][0] = MFMA32(vf[1][ks], pf0, O[1][0]);
            O[1][1] = MFMA32(vf[1][ks], pf1, O[1][1]);
        }
        __syncthreads();   // (C) PV reads done; K(mt+1) drained
    }

    #pragma unroll
    for (int reg = 0; reg < 16; ++reg) {
        float s = lacc[reg];
        #pragma unroll
        for (int off = 1; off < 32; off <<= 1) s += __shfl_xor(s, off);
        lacc[reg] = s;
    }
    if (l31 == 0) {
        #pragma unroll
        for (int reg = 0; reg < 16; ++reg) {
            int row = (reg & 3) + 8 * (reg >> 2) + 4 * h;
            l_s[mg][ng * 32 + row] = lacc[reg];
        }
    }
    __syncthreads();
    const size_t pb = (size_t)(b * 32 + nt) * 2 + ms;
    if (tid < 64) lpart[pb * 64 + tid] = l_s[0][tid] + l_s[1][tid];

    bf16* Ob = Opart + pb * 16384;
    #pragma unroll
    for (int cr = 0; cr < 2; ++cr)
        #pragma unroll
        for (int g2 = 0; g2 < 2; ++g2) {
            int n = g2 * 32 + l31;
            #pragma unroll
            for (int q2 = 0; q2 < 4; ++q2) {
                bf16x4 pk;
                #pragma unroll
                for (int j = 0; j < 4; ++j) pk.v[j] = f2b(O[cr][g2][q2 * 4 + j]);
                int c = W * 64 + cr * 32 + q2 * 8 + 4 * h;
                *(bf16x4*)&Ob[(size_t)n * 256 + c] = pk;
            }
        }
}

// ---------------------------------------------------------------------------
// outproj v4: fused reduce + bf16 Wo. Grid (256 n-tiles, 2 c-halves).
// ---------------------------------------------------------------------------
__global__ __launch_bounds__(256, 2) void outproj_kernel(
    const bf16* __restrict__ Opart, const float* __restrict__ lpart,
    const bf16* __restrict__ Wob, const float* __restrict__ bo,
    const float* __restrict__ x, float* __restrict__ out)
{
    __shared__ bf16 avs[64][260];
    __shared__ float ils[64];

    const int bx = blockIdx.x;
    const int flat0 = bx * 64;
    const int c0 = blockIdx.y * 128;
    const int tid = threadIdx.x;
    const int w = tid >> 6, lane = tid & 63;
    const int l15 = lane & 15, quad = lane >> 4;

    if (tid < 64)
        ils[tid] = 1.f / (lpart[(size_t)(bx * 2) * 64 + tid]
                        + lpart[(size_t)(bx * 2 + 1) * 64 + tid]);
    __syncthreads();

    const bf16x4* O0 = (const bf16x4*)(Opart + (size_t)(bx * 2) * 16384);
    const bf16x4* O1 = O0 + 4096;
    #pragma unroll
    for (int i = 0; i < 16; ++i) {
        int u = i * 256 + tid;
        int n = u >> 6;
        bf16x4 a = O0[u], bb = O1[u];
        float il = ils[n];
        bf16x4 o;
        #pragma unroll
        for (int t = 0; t < 4; ++t)
            o.v[t] = f2b((b2f(a.v[t]) + b2f(bb.v[t])) * il);
        *(bf16x4*)&avs[n][(u & 63) * 4] = o;
    }
    __syncthreads();

    const int bidx = flat0 >> 11, nn = flat0 & 2047;
    const size_t base = (size_t)bidx * CCH * NSEQ;

    for (int g = 0; g < 2; ++g) {
        const int cg = c0 + g * 64 + w * 16;
        const s8v* Ar = (const s8v*)(Wob + (size_t)(cg + l15) * CCH);
        s8v af[8];
        #pragma unroll
        for (int t = 0; t < 8; ++t) af[t] = Ar[t * 4 + quad];
        f4v O[4] = {};
        #pragma unroll
        for (int nt = 0; nt < 4; ++nt)
            #pragma unroll
            for (int t = 0; t < 8; ++t) {
                s8v br = *(const s8v*)&avs[nt * 16 + l15][t * 32 + quad * 8];
                O[nt] = MFMA16(af[t], br, O[nt]);
            }
        #pragma unroll
        for (int r = 0; r < 4; ++r) {
            int c = cg + quad * 4 + r;
            float bb = bo[c];
            #pragma unroll
            for (int nt = 0; nt < 4; ++nt) {
                size_t idx = base + (size_t)c * NSEQ + nn + nt * 16 + l15;
                out[idx] = O[nt][r] + bb + x[idx];
            }
        }
    }
}

// ---------------------------------------------------------------------------
extern "C" void kernel_launch(void* const* d_in, const int* in_sizes, int n_in,
                              void* d_out, int out_size, void* d_ws, size_t ws_size,
                              hipStream_t stream) {
    (void)in_sizes; (void)n_in; (void)out_size; (void)ws_size;
    const float* x  = (const float*)d_in[0];
    const float* wq = (const float*)d_in[1];
    const float* bq = (const float*)d_in[2];
    const float* wk = (const float*)d_in[3];
    const float* bk = (const float*)d_in[4];
    const float* wv = (const float*)d_in[5];
    const float* bv = (const float*)d_in[6];
    const float* wo = (const float*)d_in[7];
    const float* bo = (const float*)d_in[8];
    float* out = (float*)d_out;

    const size_t T = (size_t)BATCH * CCH * NSEQ;   // 4,194,304
    bf16* qTt  = (bf16*)d_ws;          // T64 tile-major
    bf16* kTt  = qTt + T;
    bf16* Vf   = kTt + T;              // frag-major [b][mc][cb][c32][h][8]
    bf16* wqb  = Vf + T;
    bf16* wkb  = wqb + 65536;
    bf16* wvb  = wkb + 65536;
    bf16* wob  = wvb + 65536;
    float* lpart = (float*)(wob + 65536);        // 512 * 64 f32
    bf16* Opart  = (bf16*)(lpart + 32768);       // 512 * 16384 bf16

    prepw_kernel<<<128, 256, 0, stream>>>(wq, wk, wv, wo, wqb, wkb, wvb, wob);
    qkv_kernel<<<dim3(256, 1), 256, 0, stream>>>(
        x, wqb, wkb, wvb, bq, bk, bv, qTt, kTt, Vf);
    qkv2_kernel<<<256, 256, 0, stream>>>(x, wkb, wvb, bk, bv, kTt, Vf);
    flash_kernel<<<dim3(8, 32, 2), 256, 0, stream>>>(qTt, kTt, Vf, Opart, lpart);
    outproj_kernel<<<dim3(256, 2), 256, 0, stream>>>(Opart, lpart, wob, bo, x, out);
}